// Round 5
// baseline (233.288 us; speedup 1.0000x reference)
//
#include <hip/hip_runtime.h>
#include <math.h>

#define NPG  256
#define EPG  4096
#define NG   512
#define FIN  128
#define HD   64
#define TOUT 18
#define KTOP 16
#define SRCL_CAP (EPG + 3*NPG)
#define E_TOT (NG*EPG)

// swizzled h storage: row n, col c (quad-preserving XOR -> bank spread)
__device__ __forceinline__ int hlidx(int n, int c) {
    return (n << 6) + (c ^ ((n & 7) << 2));
}
__device__ __forceinline__ float fast_tanh(float x) {
    float t = __expf(-2.0f * fabsf(x));           // monotonic in |x|
    return copysignf(__fdividef(1.0f - t, 1.0f + t), x);
}
__device__ __forceinline__ float dot4(float4 a, float4 b) {
    return a.x*b.x + a.y*b.y + a.z*b.z + a.w*b.w;
}

__launch_bounds__(1024)
__global__ void dgcnn_fused(
    const float* __restrict__ x,
    const int*   __restrict__ ei,
    const float* __restrict__ w0, const float* __restrict__ b0,
    const float* __restrict__ w1, const float* __restrict__ b1,
    const float* __restrict__ w2, const float* __restrict__ b2,
    const float* __restrict__ w3, const float* __restrict__ b3,
    const float* __restrict__ w4, const float* __restrict__ b4,
    const float* __restrict__ c1w, const float* __restrict__ c1b,
    const float* __restrict__ c2w, const float* __restrict__ c2b,
    const float* __restrict__ d1w, const float* __restrict__ d1b,
    const float* __restrict__ d2w, const float* __restrict__ d2b,
    float* __restrict__ out)
{
    __shared__ __align__(16) float s_hl[NPG*64];   // x-chunk / h_lin / h / proj rows
    __shared__ __align__(16) float wsA[8192];      // weight stage A (32KB)
    __shared__ __align__(16) float wsB[8192];      // weight stage B (32KB)
    __shared__ unsigned char s_srcl[SRCL_CAP] __attribute__((aligned(4)));
    __shared__ int   s_off[NPG+1];
    __shared__ int   s_cnt[NPG];
    __shared__ float s_invdeg[NPG];
    __shared__ float s_lin5[NPG];
    __shared__ float s_h5[NPG];
    __shared__ int   s_sel[KTOP];
    int* s_cur  = (int*)wsA;                       // phase-0 alias
    int* s_outd = (int*)(wsA + 256);               // phase-0 alias
    float* s_headf = wsB;                          // head-scratch alias (post-L3)

    const int g    = blockIdx.x;
    const int t    = threadIdx.x;
    const int lane = t & 63;
    const int wid  = t >> 6;                                   // 0..15
    const int wl   = __builtin_amdgcn_readfirstlane(wid & 7);  // channel-octet
    const int nh   = __builtin_amdgcn_readfirstlane(wid >> 3); // node half
    const int c0   = wl * 8;                                   // 8 matmul channels
    const int o0   = wl * 2;                                   // 2 proj channels
    const int n0   = nh*128 + lane;
    const int n1   = n0 + 64;
    const int js   = lane >> 4;
    const int q4   = (lane & 15) << 2;
    const int gbase = g * NPG;
    const int* __restrict__ srcg = ei + (size_t)g * EPG;
    const int* __restrict__ dstg = ei + (size_t)E_TOT + (size_t)g * EPG;

    // ---------------- phase 0: degrees + 4-padded CSR (by dst) ----------------
    if (t < NPG) { s_cnt[t] = 0; s_outd[t] = 0; }
    __syncthreads();
    for (int e = t; e < EPG; e += 1024) {
        int s = srcg[e] - gbase, d = dstg[e] - gbase;
        atomicAdd(&s_outd[s], 1);
        atomicAdd(&s_cnt[d], 1);
    }
    __syncthreads();
    if (t < NPG) s_invdeg[t] = __fdividef(1.0f, (float)(s_outd[t] + 1));
    if (wid == 0) {
        int p4 = lane * 4;
        int c0_ = s_cnt[p4], c1_ = s_cnt[p4+1], c2_ = s_cnt[p4+2], c3_ = s_cnt[p4+3];
        int q0 = (c0_+3)&~3, q1 = (c1_+3)&~3, q2 = (c2_+3)&~3, q3 = (c3_+3)&~3;
        int tot = q0+q1+q2+q3;
        int run = tot;
        #pragma unroll
        for (int o = 1; o < 64; o <<= 1) {
            int v = __shfl_up(run, o);
            if (lane >= o) run += v;
        }
        int base = run - tot;
        s_off[p4]   = base;
        s_off[p4+1] = base + q0;
        s_off[p4+2] = base + q0 + q1;
        s_off[p4+3] = base + q0 + q1 + q2;
        if (lane == 63) s_off[NPG] = run;
    }
    __syncthreads();
    if (t < NPG) s_cur[t] = s_off[t];
    __syncthreads();
    for (int e = t; e < EPG; e += 1024) {
        int s = srcg[e] - gbase, d = dstg[e] - gbase;
        int pos = atomicAdd(&s_cur[d], 1);
        s_srcl[pos] = (unsigned char)s;
    }
    __syncthreads();
    if (t < NPG) {
        int pe = s_off[t+1];
        for (int p = s_cur[t]; p < pe; p++) s_srcl[p] = (unsigned char)t;
    }
    __syncthreads();                               // CSR done; wsA free

    float pacc[2][2];                              // conv1 proj accum (2 nodes x 2 out)
    pacc[0][0] = pacc[0][1] = pacc[1][0] = pacc[1][1] = 0.f;

    // agg: h[d] = tanh(invdeg*(sum_src h_lin[src] + h_lin[d])); results in regs
    auto aggregate = [&]() {
        float4 res[4];
        #pragma unroll
        for (int r = 0; r < 4; r++) {
            int d = (wid + 16*r)*4 + js;
            int off = s_off[d], pe = s_off[d+1];
            int npad = (pe - off) - s_cnt[d];
            float4 a = *(const float4*)&s_hl[hlidx(d, q4)];
            float cf = (float)(1 - npad);
            a.x *= cf; a.y *= cf; a.z *= cf; a.w *= cf;
            for (int e = off; e < pe; e += 4) {
                unsigned sq = *(const unsigned*)&s_srcl[e];
                #pragma unroll
                for (int m = 0; m < 4; m++) {
                    int src = (sq >> (8*m)) & 255;
                    float4 hv = *(const float4*)&s_hl[hlidx(src, q4)];
                    a.x += hv.x; a.y += hv.y; a.z += hv.z; a.w += hv.w;
                }
            }
            float id = s_invdeg[d];
            res[r].x = fast_tanh(a.x * id); res[r].y = fast_tanh(a.y * id);
            res[r].z = fast_tanh(a.z * id); res[r].w = fast_tanh(a.w * id);
        }
        __syncthreads();
        #pragma unroll
        for (int r = 0; r < 4; r++) {
            int d = (wid + 16*r)*4 + js;
            *(float4*)&s_hl[hlidx(d, q4)] = res[r];
        }
        __syncthreads();
    };

    // 64->64 matmul (+optional proj) from LDS weights; writes h_lin, 2 barriers
    auto mm64 = [&](const float* wc, const float* bp, bool doProj) {
        float acc0[8], acc1[8];
        #pragma unroll
        for (int j = 0; j < 8; j++) { float bv = bp[c0+j]; acc0[j] = bv; acc1[j] = bv; }
        #pragma unroll 2
        for (int kq = 0; kq < 16; kq++) {
            float4 h0 = *(const float4*)&s_hl[hlidx(n0, kq*4)];
            float4 h1 = *(const float4*)&s_hl[hlidx(n1, kq*4)];
            #pragma unroll
            for (int j = 0; j < 8; j++) {
                float4 wq = *(const float4*)&wc[(c0+j)*HD + kq*4];
                acc0[j] += dot4(h0, wq);
                acc1[j] += dot4(h1, wq);
            }
            if (doProj) {
                #pragma unroll
                for (int p = 0; p < 2; p++) {
                    float4 cq = *(const float4*)&wc[4096 + (o0+p)*HD + kq*4];
                    pacc[0][p] += dot4(h0, cq);
                    pacc[1][p] += dot4(h1, cq);
                }
            }
        }
        __syncthreads();                           // all reads of h done
        { float4 v = {acc0[0],acc0[1],acc0[2],acc0[3]}; *(float4*)&s_hl[hlidx(n0, c0)]   = v; }
        { float4 v = {acc0[4],acc0[5],acc0[6],acc0[7]}; *(float4*)&s_hl[hlidx(n0, c0+4)] = v; }
        { float4 v = {acc1[0],acc1[1],acc1[2],acc1[3]}; *(float4*)&s_hl[hlidx(n1, c0)]   = v; }
        { float4 v = {acc1[4],acc1[5],acc1[6],acc1[7]}; *(float4*)&s_hl[hlidx(n1, c0+4)] = v; }
        __syncthreads();
    };

    // ---------------- layer 0 (F=128; x in 2 LDS chunks; acc in regs) ---------
    {
        // stage w0 (32KB) + x chunk0
        for (int i = t; i < 8192; i += 1024) wsA[i] = w0[i];
        {
            int n = t >> 2, sub = t & 3;
            const float4* xp = (const float4*)&x[(size_t)(gbase+n)*FIN + sub*16];
            float4 v0 = xp[0], v1 = xp[1], v2 = xp[2], v3 = xp[3];
            *(float4*)&s_hl[hlidx(n, sub*16 + 0)]  = v0;
            *(float4*)&s_hl[hlidx(n, sub*16 + 4)]  = v1;
            *(float4*)&s_hl[hlidx(n, sub*16 + 8)]  = v2;
            *(float4*)&s_hl[hlidx(n, sub*16 + 12)] = v3;
        }
        __syncthreads();

        float acc0[8], acc1[8];
        #pragma unroll
        for (int j = 0; j < 8; j++) { float bv = b0[c0+j]; acc0[j] = bv; acc1[j] = bv; }

        // stage next-layer weights (w1 + c1w slice 0) into wsB, overlapped
        for (int i = t; i < 4096; i += 1024) wsB[i] = w1[i];
        { int o = t >> 6, k = t & 63; wsB[4096 + o*64 + k] = c1w[o*257 + k]; }

        #pragma unroll 2
        for (int kq = 0; kq < 16; kq++) {          // chunk 0: k = 0..63
            float4 h0 = *(const float4*)&s_hl[hlidx(n0, kq*4)];
            float4 h1 = *(const float4*)&s_hl[hlidx(n1, kq*4)];
            #pragma unroll
            for (int j = 0; j < 8; j++) {
                float4 wq = *(const float4*)&wsA[(c0+j)*FIN + kq*4];
                acc0[j] += dot4(h0, wq);
                acc1[j] += dot4(h1, wq);
            }
        }
        __syncthreads();
        {   // stage x chunk1
            int n = t >> 2, sub = t & 3;
            const float4* xp = (const float4*)&x[(size_t)(gbase+n)*FIN + 64 + sub*16];
            float4 v0 = xp[0], v1 = xp[1], v2 = xp[2], v3 = xp[3];
            *(float4*)&s_hl[hlidx(n, sub*16 + 0)]  = v0;
            *(float4*)&s_hl[hlidx(n, sub*16 + 4)]  = v1;
            *(float4*)&s_hl[hlidx(n, sub*16 + 8)]  = v2;
            *(float4*)&s_hl[hlidx(n, sub*16 + 12)] = v3;
        }
        __syncthreads();
        #pragma unroll 2
        for (int kq = 0; kq < 16; kq++) {          // chunk 1: k = 64..127
            float4 h0 = *(const float4*)&s_hl[hlidx(n0, kq*4)];
            float4 h1 = *(const float4*)&s_hl[hlidx(n1, kq*4)];
            #pragma unroll
            for (int j = 0; j < 8; j++) {
                float4 wq = *(const float4*)&wsA[(c0+j)*FIN + 64 + kq*4];
                acc0[j] += dot4(h0, wq);
                acc1[j] += dot4(h1, wq);
            }
        }
        __syncthreads();                           // chunk1 reads done
        { float4 v = {acc0[0],acc0[1],acc0[2],acc0[3]}; *(float4*)&s_hl[hlidx(n0, c0)]   = v; }
        { float4 v = {acc0[4],acc0[5],acc0[6],acc0[7]}; *(float4*)&s_hl[hlidx(n0, c0+4)] = v; }
        { float4 v = {acc1[0],acc1[1],acc1[2],acc1[3]}; *(float4*)&s_hl[hlidx(n1, c0)]   = v; }
        { float4 v = {acc1[4],acc1[5],acc1[6],acc1[7]}; *(float4*)&s_hl[hlidx(n1, c0+4)] = v; }
        __syncthreads();
    }
    aggregate();                                   // -> hidden[0]

    // ---------------- layer 1 (reads wsB; stage w2+slice64 -> wsA) ------------
    for (int i = t; i < 4096; i += 1024) wsA[i] = w2[i];
    { int o = t >> 6, k = t & 63; wsA[4096 + o*64 + k] = c1w[o*257 + 64 + k]; }
    mm64(wsB, b1, true);
    aggregate();                                   // -> hidden[1]

    // ---------------- layer 2 (reads wsA; stage w3+slice128 -> wsB) -----------
    for (int i = t; i < 4096; i += 1024) wsB[i] = w3[i];
    { int o = t >> 6, k = t & 63; wsB[4096 + o*64 + k] = c1w[o*257 + 128 + k]; }
    mm64(wsA, b2, true);
    aggregate();                                   // -> hidden[2]

    // ---------------- layer 3 (reads wsB; stage slice192+w4+col256 -> wsA) ----
    { int o = t >> 6, k = t & 63; wsA[4096 + o*64 + k] = c1w[o*257 + 192 + k]; }
    if (t < 64) wsA[5120 + t] = w4[t];
    if (t < 16) wsA[5184 + t] = c1w[t*257 + 256];
    mm64(wsB, b3, true);
    aggregate();                                   // -> hidden[3]

    // ---------------- layer 4 (64->1) + proj(hidden[3]) -----------------------
    {
        float l50 = 0.f, l51 = 0.f;
        #pragma unroll 2
        for (int kq = 0; kq < 16; kq++) {
            float4 h0 = *(const float4*)&s_hl[hlidx(n0, kq*4)];
            float4 h1 = *(const float4*)&s_hl[hlidx(n1, kq*4)];
            #pragma unroll
            for (int p = 0; p < 2; p++) {
                float4 cq = *(const float4*)&wsA[4096 + (o0+p)*HD + kq*4];
                pacc[0][p] += dot4(h0, cq);
                pacc[1][p] += dot4(h1, cq);
            }
            if (wl == 0) {
                float4 w4q = *(const float4*)&wsA[5120 + kq*4];
                l50 += dot4(h0, w4q);
                l51 += dot4(h1, w4q);
            }
        }
        if (wl == 0) {
            float b4v = b4[0];
            s_lin5[n0] = l50 + b4v;
            s_lin5[n1] = l51 + b4v;
        }
        __syncthreads();
        if (t < NPG) {
            int d = t;
            int off = s_off[d], pe = s_off[d+1];
            int npad = (pe - off) - s_cnt[d];
            float a = (float)(1 - npad) * s_lin5[d];
            for (int e = off; e < pe; e += 4) {
                unsigned sq = *(const unsigned*)&s_srcl[e];
                a += s_lin5[sq & 255] + s_lin5[(sq>>8)&255]
                   + s_lin5[(sq>>16)&255] + s_lin5[(sq>>24)&255];
            }
            s_h5[d] = fast_tanh(a * s_invdeg[d]);
        }
        __syncthreads();                           // also: all hidden[3] reads done
        {
            float cA = wsA[5184 + o0], cB = wsA[5184 + o0 + 1];
            float h50 = s_h5[n0], h51 = s_h5[n1];
            s_hl[n0*16 + o0]     = pacc[0][0] + h50*cA;
            s_hl[n0*16 + o0 + 1] = pacc[0][1] + h50*cB;
            s_hl[n1*16 + o0]     = pacc[1][0] + h51*cA;
            s_hl[n1*16 + o0 + 1] = pacc[1][1] + h51*cB;
        }
    }
    __syncthreads();

    // ---------------- top-16 (desc value, asc index ties) ----------------
    if (wid == 0) {
        float v[4]; int idx[4];
        int p4 = lane * 4;
        #pragma unroll
        for (int j = 0; j < 4; j++) { idx[j] = p4 + j; v[j] = s_h5[p4 + j]; }
        for (int r = 0; r < KTOP; r++) {
            float bv = v[0]; int bi = idx[0];
            #pragma unroll
            for (int j = 1; j < 4; j++)
                if (v[j] > bv || (v[j] == bv && idx[j] < bi)) { bv = v[j]; bi = idx[j]; }
            #pragma unroll
            for (int o = 32; o > 0; o >>= 1) {
                float ov = __shfl_xor(bv, o);
                int   oi = __shfl_xor(bi, o);
                if (ov > bv || (ov == bv && oi < bi)) { bv = ov; bi = oi; }
            }
            if ((bi >> 2) == lane) v[bi & 3] = -1e30f;
            if (lane == 0) s_sel[r] = bi;
        }
    }
    __syncthreads();

    // ---------------- head (scratch aliased over wsB) ----------------
    float* s_c1   = s_headf;        // [16 o][16 slot]
    float* s_p1   = s_headf + 256;  // [16 o][8]
    float* s_flat = s_headf + 384;  // 128
    float* s_last = s_headf + 512;  // 32
    float* s_outv = s_headf + 544;  // 18

    if (t < 256) {
        int sl = t >> 4, o = t & 15;
        float vv = s_hl[s_sel[sl]*16 + o] + c1b[o];
        s_c1[o*16 + sl] = fmaxf(vv, 0.f);
    }
    __syncthreads();
    if (t < 128) {
        int o = t >> 3, j = t & 7;
        s_p1[o*8 + j] = fmaxf(s_c1[o*16 + 2*j], s_c1[o*16 + 2*j + 1]);
    }
    __syncthreads();
    if (t < 128) {
        int oc = t >> 2, tt = t & 3;
        float a = c2b[oc];
        #pragma unroll
        for (int ic = 0; ic < 16; ic++)
            #pragma unroll
            for (int kk = 0; kk < 5; kk++)
                a += s_p1[ic*8 + tt + kk] * c2w[(oc*16 + ic)*5 + kk];
        s_flat[oc*4 + tt] = fmaxf(a, 0.f);
    }
    __syncthreads();
    if (t < 32) {
        float a = d1b[t];
        #pragma unroll 16
        for (int i = 0; i < 128; i++) a += s_flat[i] * d1w[t*128 + i];
        a = fmaxf(a, 0.f);
        s_last[t] = a;
        out[2*NG*TOUT + g*32 + t] = a;             // output 2: last
    }
    __syncthreads();
    if (t < TOUT) {
        float a = d2b[t];
        #pragma unroll
        for (int j = 0; j < 32; j++) a += s_last[j] * d2w[t*32 + j];
        s_outv[t] = a;
        out[NG*TOUT + g*TOUT + t] = a;             // output 1: logits
    }
    __syncthreads();
    if (t < TOUT) {
        float m = s_outv[0];
        for (int i = 1; i < TOUT; i++) m = fmaxf(m, s_outv[i]);
        float sum = 0.f;
        for (int i = 0; i < TOUT; i++) sum += expf(s_outv[i] - m);
        out[g*TOUT + t] = s_outv[t] - m - logf(sum);   // output 0: log_softmax
    }
}

extern "C" void kernel_launch(void* const* d_in, const int* in_sizes, int n_in,
                              void* d_out, int out_size, void* d_ws, size_t ws_size,
                              hipStream_t stream) {
    (void)in_sizes; (void)n_in; (void)out_size; (void)d_ws; (void)ws_size;
    const float* x   = (const float*)d_in[0];
    const int*   ei  = (const int*)  d_in[1];
    const float* w0  = (const float*)d_in[4];  const float* b0 = (const float*)d_in[5];
    const float* w1  = (const float*)d_in[6];  const float* b1 = (const float*)d_in[7];
    const float* w2  = (const float*)d_in[8];  const float* b2 = (const float*)d_in[9];
    const float* w3  = (const float*)d_in[10]; const float* b3 = (const float*)d_in[11];
    const float* w4  = (const float*)d_in[12]; const float* b4 = (const float*)d_in[13];
    const float* c1w = (const float*)d_in[14]; const float* c1b = (const float*)d_in[15];
    const float* c2w = (const float*)d_in[16]; const float* c2b = (const float*)d_in[17];
    const float* d1w = (const float*)d_in[18]; const float* d1b = (const float*)d_in[19];
    const float* d2w = (const float*)d_in[20]; const float* d2b = (const float*)d_in[21];
    float* out = (float*)d_out;

    dgcnn_fused<<<NG, 1024, 0, stream>>>(x, ei,
        w0, b0, w1, b1, w2, b2, w3, b3, w4, b4,
        c1w, c1b, c2w, c2b, d1w, d1b, d2w, d2b, out);
}

// Round 6
// 228.365 us; speedup vs baseline: 1.0216x; 1.0216x over previous
//
#include <hip/hip_runtime.h>
#include <math.h>

#define NPG 256
#define EPG 4096
#define NG  512
#define FIN 128
#define HD  64
#define TOUT 18
#define KTOP 16
#define STA 68                    // h row stride (floats); b128 patterns conflict-free
#define SRCL_CAP (EPG + 3*NPG)
#define E_TOT (NG*EPG)

__launch_bounds__(1024, 8)        // 8 waves/EU -> 2 blocks/CU
__global__ void dgcnn_fused(
    const float* __restrict__ x,
    const int*   __restrict__ ei,
    const float* __restrict__ w0, const float* __restrict__ b0,
    const float* __restrict__ w1, const float* __restrict__ b1,
    const float* __restrict__ w2, const float* __restrict__ b2,
    const float* __restrict__ w3, const float* __restrict__ b3,
    const float* __restrict__ w4, const float* __restrict__ b4,
    const float* __restrict__ c1w, const float* __restrict__ c1b,
    const float* __restrict__ c2w, const float* __restrict__ c2b,
    const float* __restrict__ d1w, const float* __restrict__ d1b,
    const float* __restrict__ d2w, const float* __restrict__ d2b,
    float* __restrict__ out)
{
    __shared__ __align__(16) float s_h[NPG*STA];   // x-chunk / h_lin / h / proj+head (aliased)
    __shared__ unsigned char s_srcl[SRCL_CAP] __attribute__((aligned(4)));
    __shared__ int   s_off[NPG+1];
    __shared__ int   s_cnt[NPG];
    __shared__ float s_invdeg[NPG];
    __shared__ float s_lin5[NPG];
    __shared__ float s_h5[NPG];
    __shared__ int   s_sel[KTOP];
    int*   s_cur   = (int*)s_h;            // phase-0 alias (rows 0..3)
    int*   s_outd  = ((int*)s_h) + NPG;    // phase-0 alias (rows 3..7)
    float* s_proj  = s_h;                  // final alias: [256][20] proj rows
    float* s_headf = s_h + 8192;           // head scratch (beyond proj 5120)

    const int g    = blockIdx.x;
    const int t    = threadIdx.x;
    const int lane = t & 63;
    const int wid  = t >> 6;                                    // 0..15
    const int n    = t & 255;                                   // owned node
    const int cq   = __builtin_amdgcn_readfirstlane(t >> 8);    // 0..3 (wave-uniform)
    const int js   = lane >> 4;
    const int q4   = (lane & 15) << 2;
    const int gbase = g * NPG;
    const int* __restrict__ srcg = ei + (size_t)g * EPG;
    const int* __restrict__ dstg = ei + (size_t)E_TOT + (size_t)g * EPG;

    // ---------------- phase 0: degrees + 4-padded CSR (by dst) ----------------
    if (t < NPG) { s_cnt[t] = 0; s_outd[t] = 0; }
    __syncthreads();
    for (int e = t; e < EPG; e += 1024) {
        int s = srcg[e] - gbase, d = dstg[e] - gbase;
        atomicAdd(&s_outd[s], 1);
        atomicAdd(&s_cnt[d], 1);
    }
    __syncthreads();
    if (t < NPG) s_invdeg[t] = __fdividef(1.0f, (float)(s_outd[t] + 1));
    if (wid == 0) {
        int p4 = lane * 4;
        int c0_ = s_cnt[p4], c1_ = s_cnt[p4+1], c2_ = s_cnt[p4+2], c3_ = s_cnt[p4+3];
        int q0 = (c0_+3)&~3, q1 = (c1_+3)&~3, q2 = (c2_+3)&~3, q3 = (c3_+3)&~3;
        int tot = q0+q1+q2+q3;
        int run = tot;
        #pragma unroll
        for (int o = 1; o < 64; o <<= 1) {
            int v = __shfl_up(run, o);
            if (lane >= o) run += v;
        }
        int base = run - tot;
        s_off[p4]   = base;
        s_off[p4+1] = base + q0;
        s_off[p4+2] = base + q0 + q1;
        s_off[p4+3] = base + q0 + q1 + q2;
        if (lane == 63) s_off[NPG] = run;
    }
    __syncthreads();
    if (t < NPG) s_cur[t] = s_off[t];
    __syncthreads();
    for (int e = t; e < EPG; e += 1024) {
        int s = srcg[e] - gbase, d = dstg[e] - gbase;
        int pos = atomicAdd(&s_cur[d], 1);
        s_srcl[pos] = (unsigned char)s;
    }
    __syncthreads();
    if (t < NPG) {                                   // pad to x4 with sentinel src=t (self)
        int pe = s_off[t+1];
        for (int p = s_cur[t]; p < pe; p++) s_srcl[p] = (unsigned char)t;
    }
    __syncthreads();                                 // CSR done; s_h aliases dead

    float proj[4] = {0.f, 0.f, 0.f, 0.f};            // conv1 outputs 4cq..4cq+3 of node n

    // agg (in place): h[d] = tanh(invdeg*(sum_src hl[src] + hl[d]))
    auto aggregate = [&]() {
        float4 res[4];
        #pragma unroll
        for (int r = 0; r < 4; r++) {
            int d = (wid + 16*r)*4 + js;
            int off = s_off[d], pe = s_off[d+1];
            int npad = (pe - off) - s_cnt[d];
            float4 a = *(const float4*)&s_h[d*STA + q4];
            float cf = (float)(1 - npad);
            a.x *= cf; a.y *= cf; a.z *= cf; a.w *= cf;
            for (int e = off; e < pe; e += 4) {
                unsigned sq = *(const unsigned*)&s_srcl[e];
                #pragma unroll
                for (int m = 0; m < 4; m++) {
                    int src = (sq >> (8*m)) & 255;
                    float4 hv = *(const float4*)&s_h[src*STA + q4];
                    a.x += hv.x; a.y += hv.y; a.z += hv.z; a.w += hv.w;
                }
            }
            float id = s_invdeg[d];
            res[r].x = tanhf(a.x * id); res[r].y = tanhf(a.y * id);
            res[r].z = tanhf(a.z * id); res[r].w = tanhf(a.w * id);
        }
        __syncthreads();                             // all reads of h_lin complete
        #pragma unroll
        for (int r = 0; r < 4; r++) {
            int d = (wid + 16*r)*4 + js;
            *(float4*)&s_h[d*STA + q4] = res[r];
        }
        __syncthreads();
    };

    // hidden matmul (64->64) + folded conv1-proj slice; own-row reads, uniform weights
    auto mmHidden = [&](const float* __restrict__ w, const float* __restrict__ b,
                        const float* __restrict__ c1s) {
        float acc[16];
        #pragma unroll
        for (int j = 0; j < 16; j++) acc[j] = b[cq*16 + j];
        const float* wb = w + (cq*16)*HD;
        const float* cb = c1s + (cq*4)*257;
        #pragma unroll 2
        for (int kq = 0; kq < 16; kq++) {
            float4 hv = *(const float4*)&s_h[n*STA + kq*4];
            #pragma unroll
            for (int j = 0; j < 16; j++) {
                float4 wq = *(const float4*)(wb + j*HD + kq*4);   // uniform s_load_dwordx4
                acc[j] += hv.x*wq.x + hv.y*wq.y + hv.z*wq.z + hv.w*wq.w;
            }
            #pragma unroll
            for (int p = 0; p < 4; p++) {
                const float* cp = cb + p*257 + kq*4;              // unaligned -> scalar dwords
                proj[p] += hv.x*cp[0] + hv.y*cp[1] + hv.z*cp[2] + hv.w*cp[3];
            }
        }
        __syncthreads();                             // all reads of h done
        #pragma unroll
        for (int j = 0; j < 4; j++) {
            float4 v = {acc[4*j], acc[4*j+1], acc[4*j+2], acc[4*j+3]};
            *(float4*)&s_h[n*STA + cq*16 + 4*j] = v;
        }
        __syncthreads();
    };

    // ---------------- layer 0 (F=128, x staged in 2 chunks, acc in regs) ------
    {
        float acc[16];
        #pragma unroll
        for (int j = 0; j < 16; j++) acc[j] = b0[cq*16 + j];
        for (int c2 = 0; c2 < 2; c2++) {
            {   // stage x[:, c2*64 .. +63] into s_h[n][0..63] (coalesced 64B/thread)
                int sn = t >> 2, sq = t & 3;
                const float4* xp = (const float4*)(x + (size_t)(gbase+sn)*FIN + c2*64 + sq*16);
                float4 a0 = xp[0], a1 = xp[1], a2 = xp[2], a3 = xp[3];
                *(float4*)&s_h[sn*STA + sq*16 + 0]  = a0;
                *(float4*)&s_h[sn*STA + sq*16 + 4]  = a1;
                *(float4*)&s_h[sn*STA + sq*16 + 8]  = a2;
                *(float4*)&s_h[sn*STA + sq*16 + 12] = a3;
            }
            __syncthreads();
            const float* wb = w0 + (cq*16)*FIN + c2*64;
            #pragma unroll 2
            for (int kq = 0; kq < 16; kq++) {
                float4 hv = *(const float4*)&s_h[n*STA + kq*4];
                #pragma unroll
                for (int j = 0; j < 16; j++) {
                    float4 wq = *(const float4*)(wb + j*FIN + kq*4);
                    acc[j] += hv.x*wq.x + hv.y*wq.y + hv.z*wq.z + hv.w*wq.w;
                }
            }
            __syncthreads();                         // chunk reads done (before restage)
        }
        #pragma unroll
        for (int j = 0; j < 4; j++) {
            float4 v = {acc[4*j], acc[4*j+1], acc[4*j+2], acc[4*j+3]};
            *(float4*)&s_h[n*STA + cq*16 + 4*j] = v;
        }
        __syncthreads();
    }
    aggregate();                                     // -> h0

    mmHidden(w1, b1, c1w);                           // h0 -> hl1, proj slice 0
    aggregate();                                     // -> h1
    mmHidden(w2, b2, c1w + 64);                      // h1 -> hl2, proj slice 64
    aggregate();                                     // -> h2
    mmHidden(w3, b3, c1w + 128);                     // h2 -> hl3, proj slice 128
    aggregate();                                     // -> h3

    // ---------------- layer 4 (64->1) + proj slice 192 -----------------------
    {
        const float* cb = c1w + (cq*4)*257 + 192;
        float l5 = 0.f;
        #pragma unroll 2
        for (int kq = 0; kq < 16; kq++) {
            float4 hv = *(const float4*)&s_h[n*STA + kq*4];
            #pragma unroll
            for (int p = 0; p < 4; p++) {
                const float* cp = cb + p*257 + kq*4;
                proj[p] += hv.x*cp[0] + hv.y*cp[1] + hv.z*cp[2] + hv.w*cp[3];
            }
            if (cq == 0) {
                l5 += hv.x*w4[kq*4] + hv.y*w4[kq*4+1] + hv.z*w4[kq*4+2] + hv.w*w4[kq*4+3];
            }
        }
        if (cq == 0) s_lin5[n] = l5 + b4[0];
        __syncthreads();                             // all h3 reads done; lin5 ready
        if (t < NPG) {
            int d = t;
            int off = s_off[d], pe = s_off[d+1];
            int npad = (pe - off) - s_cnt[d];
            float a = (float)(1 - npad) * s_lin5[d];
            for (int e = off; e < pe; e += 4) {
                unsigned sq = *(const unsigned*)&s_srcl[e];
                a += s_lin5[sq & 255] + s_lin5[(sq>>8)&255]
                   + s_lin5[(sq>>16)&255] + s_lin5[(sq>>24)&255];
            }
            s_h5[d] = tanhf(a * s_invdeg[d]);
        }
        __syncthreads();
        {   // finalize proj with h5 term; store proj rows (s_h alias now safe)
            float h5v = s_h5[n];
            #pragma unroll
            for (int p = 0; p < 4; p++) proj[p] += h5v * c1w[(cq*4+p)*257 + 256];
            float4 v = {proj[0], proj[1], proj[2], proj[3]};
            *(float4*)&s_proj[n*20 + cq*4] = v;
        }
        if (wid == 0) {                              // top-16: desc value, asc index ties
            float v[4]; int idx[4];
            int p4 = lane * 4;
            #pragma unroll
            for (int j = 0; j < 4; j++) { idx[j] = p4 + j; v[j] = s_h5[p4 + j]; }
            for (int r = 0; r < KTOP; r++) {
                float bv = v[0]; int bi = idx[0];
                #pragma unroll
                for (int j = 1; j < 4; j++)
                    if (v[j] > bv || (v[j] == bv && idx[j] < bi)) { bv = v[j]; bi = idx[j]; }
                #pragma unroll
                for (int o = 32; o > 0; o >>= 1) {
                    float ov = __shfl_xor(bv, o);
                    int   oi = __shfl_xor(bi, o);
                    if (ov > bv || (ov == bv && oi < bi)) { bv = ov; bi = oi; }
                }
                if ((bi >> 2) == lane) v[bi & 3] = -1e30f;
                if (lane == 0) s_sel[r] = bi;
            }
        }
    }
    __syncthreads();

    // ---------------- head ----------------
    float* s_c1   = s_headf;        // [16 o][16 slot]
    float* s_p1   = s_headf + 256;  // [16 o][8]
    float* s_flat = s_headf + 384;  // 128
    float* s_last = s_headf + 512;  // 32
    float* s_outv = s_headf + 544;  // 18

    if (t < 256) {
        int sl = t >> 4, o = t & 15;
        float vv = s_proj[s_sel[sl]*20 + o] + c1b[o];
        s_c1[o*16 + sl] = fmaxf(vv, 0.f);
    }
    __syncthreads();
    if (t < 128) {
        int o = t >> 3, j = t & 7;
        s_p1[o*8 + j] = fmaxf(s_c1[o*16 + 2*j], s_c1[o*16 + 2*j + 1]);
    }
    __syncthreads();
    if (t < 128) {
        int oc = t >> 2, tt = t & 3;
        float a = c2b[oc];
        #pragma unroll
        for (int ic = 0; ic < 16; ic++)
            #pragma unroll
            for (int kk = 0; kk < 5; kk++)
                a += s_p1[ic*8 + tt + kk] * c2w[(oc*16 + ic)*5 + kk];
        s_flat[oc*4 + tt] = fmaxf(a, 0.f);
    }
    __syncthreads();
    if (t < 32) {
        float a = d1b[t];
        #pragma unroll 16
        for (int i = 0; i < 128; i++) a += s_flat[i] * d1w[t*128 + i];
        a = fmaxf(a, 0.f);
        s_last[t] = a;
        out[2*NG*TOUT + g*32 + t] = a;               // output 2: last
    }
    __syncthreads();
    if (t < TOUT) {
        float a = d2b[t];
        #pragma unroll
        for (int j = 0; j < 32; j++) a += s_last[j] * d2w[t*32 + j];
        s_outv[t] = a;
        out[NG*TOUT + g*TOUT + t] = a;               // output 1: logits
    }
    __syncthreads();
    if (t < TOUT) {
        float m = s_outv[0];
        for (int i = 1; i < TOUT; i++) m = fmaxf(m, s_outv[i]);
        float sum = 0.f;
        for (int i = 0; i < TOUT; i++) sum += expf(s_outv[i] - m);
        out[g*TOUT + t] = s_outv[t] - m - logf(sum); // output 0: log_softmax
    }
}

extern "C" void kernel_launch(void* const* d_in, const int* in_sizes, int n_in,
                              void* d_out, int out_size, void* d_ws, size_t ws_size,
                              hipStream_t stream) {
    (void)in_sizes; (void)n_in; (void)out_size; (void)d_ws; (void)ws_size;
    const float* x   = (const float*)d_in[0];
    const int*   ei  = (const int*)  d_in[1];
    const float* w0  = (const float*)d_in[4];  const float* b0 = (const float*)d_in[5];
    const float* w1  = (const float*)d_in[6];  const float* b1 = (const float*)d_in[7];
    const float* w2  = (const float*)d_in[8];  const float* b2 = (const float*)d_in[9];
    const float* w3  = (const float*)d_in[10]; const float* b3 = (const float*)d_in[11];
    const float* w4  = (const float*)d_in[12]; const float* b4 = (const float*)d_in[13];
    const float* c1w = (const float*)d_in[14]; const float* c1b = (const float*)d_in[15];
    const float* c2w = (const float*)d_in[16]; const float* c2b = (const float*)d_in[17];
    const float* d1w = (const float*)d_in[18]; const float* d1b = (const float*)d_in[19];
    const float* d2w = (const float*)d_in[20]; const float* d2b = (const float*)d_in[21];
    float* out = (float*)d_out;

    dgcnn_fused<<<NG, 1024, 0, stream>>>(x, ei,
        w0, b0, w1, b1, w2, b2, w3, b3, w4, b4,
        c1w, c1b, c2w, c2b, d1w, d1b, d2w, d2b, out);
}